// Round 2
// baseline (798.185 us; speedup 1.0000x reference)
//
#include <hip/hip_runtime.h>
#include <stdint.h>

typedef __bf16 bf16;
typedef __bf16 bf16x8 __attribute__((ext_vector_type(8)));
typedef __bf16 bf16x4 __attribute__((ext_vector_type(4)));
typedef float  f32x4  __attribute__((ext_vector_type(4)));

#define MFMA16(a,b,c) __builtin_amdgcn_mfma_f32_16x16x32_bf16((a),(b),(c),0,0,0)

__device__ __forceinline__ void gl16(const bf16* g, bf16* l) {
  __builtin_amdgcn_global_load_lds((const __attribute__((address_space(1))) void*)g,
                                   (__attribute__((address_space(3))) void*)l, 16, 0, 0);
}

// ---- ws layout (bf16 element offsets) ----
#define OFF_XB     0LL
#define OFF_WAB    8388608LL   // [128][1024]: rows 0-63 = w_kv_a, 64-127 = w_q_a
#define OFF_WKVB   8519680LL   // [2048][64]
#define OFF_WQB    8650752LL   // [1024][64]
#define OFF_WPROJ  8716288LL   // [1024][1024]
#define OFF_LATN   9764864LL   // [8192][128] normalized latents (kv | q)
#define OFF_K      10813440LL  // [64 bh][2048 t][64 d]
#define OFF_VT     19202048LL  // [64 bh][64 d][2048 t]  (V transposed)
#define OFF_Q      27590656LL  // [64 bh][2048 t][64 d]  (pre-scaled by 0.125)
#define OFF_Y      35979264LL  // [4 b][2048 t][1024 hd]

// ============================ convert fp32 -> bf16 ============================
__global__ __launch_bounds__(256) void k_convert(
    const float* __restrict__ x, const float* __restrict__ wkva, const float* __restrict__ wkvb,
    const float* __restrict__ wqa, const float* __restrict__ wqb, const float* __restrict__ wproj,
    bf16* __restrict__ ws)
{
  int64_t q = (int64_t)blockIdx.x * 256 + threadIdx.x;   // float4-quad index
  const float* src; bf16* dst;
  if (q < 2097152LL)      { src = x + 4*q;                          dst = ws + OFF_XB + 4*q; }
  else if (q < 2129920LL) { int64_t e = 4*(q - 2097152LL);
                            int row = (int)(e >> 10), col = (int)(e & 1023);
                            src = (row < 64) ? (wkva + ((int64_t)row << 10) + col)
                                             : (wqa + ((int64_t)(row - 64) << 10) + col);
                            dst = ws + OFF_WAB + e; }
  else if (q < 2162688LL) { int64_t j = q - 2129920LL; src = wkvb + 4*j; dst = ws + OFF_WKVB + 4*j; }
  else if (q < 2179072LL) { int64_t j = q - 2162688LL; src = wqb  + 4*j; dst = ws + OFF_WQB  + 4*j; }
  else if (q < 2441216LL) { int64_t j = q - 2179072LL; src = wproj+ 4*j; dst = ws + OFF_WPROJ+ 4*j; }
  else return;
  float4 v = *(const float4*)src;
  bf16x4 o; o.x = (bf16)v.x; o.y = (bf16)v.y; o.z = (bf16)v.z; o.w = (bf16)v.w;
  *(bf16x4*)dst = o;
}

// ================= shared 128x128-tile GEMM mainloop (C = A @ B^T) =================
// LDS tiles are [128 rows][8 chunks of 16B], XOR-swizzled: physical chunk p at
// (row,p) holds logical chunk c = p ^ (row&7). global_load_lds keeps LDS linear
// (phys byte = tid*16); the SOURCE column is pre-swizzled (rule #21).
__device__ __forceinline__ void gemm_core(
    const bf16* __restrict__ A, const bf16* __restrict__ B,
    int lda, int ldb, int K, int m0, int n0,
    bf16* As, bf16* Bs, f32x4 acc[4][4])
{
  const int tid = threadIdx.x, lane = tid & 63;
  const int wr = tid >> 7, wc = (tid >> 6) & 1;
  const int r0 = tid >> 3, c0 = (tid & 7) * 8;
  const int csw = (((tid & 7) ^ (r0 & 7)) * 8);     // swizzled source col (elements)
  const int fr = lane & 15, fg = lane >> 4;
#pragma unroll
  for (int mi = 0; mi < 4; mi++)
#pragma unroll
    for (int ni = 0; ni < 4; ni++) acc[mi][ni] = (f32x4){0.f, 0.f, 0.f, 0.f};
  for (int kt = 0; kt < K; kt += 64) {
#pragma unroll
    for (int p = 0; p < 4; p++) {
      int row = p * 32 + r0;
      gl16(A + (int64_t)(m0 + row) * lda + kt + csw, As + row * 64 + c0);
      gl16(B + (int64_t)(n0 + row) * ldb + kt + csw, Bs + row * 64 + c0);
    }
    __syncthreads();   // drains vmcnt (global_load_lds) + barrier
#pragma unroll
    for (int kk = 0; kk < 2; kk++) {
      bf16x8 af[4], bfr[4];
#pragma unroll
      for (int i = 0; i < 4; i++) {
        af[i]  = *(const bf16x8*)(As + (wr * 64 + i * 16 + fr) * 64 + (((kk * 4 + fg) ^ (fr & 7)) * 8));
        bfr[i] = *(const bf16x8*)(Bs + (wc * 64 + i * 16 + fr) * 64 + (((kk * 4 + fg) ^ (fr & 7)) * 8));
      }
#pragma unroll
      for (int mi = 0; mi < 4; mi++)
#pragma unroll
        for (int ni = 0; ni < 4; ni++)
          acc[mi][ni] = MFMA16(af[mi], bfr[ni], acc[mi][ni]);
    }
    __syncthreads();
  }
}

// =================== latent GEMM + fused RMSNorm epilogue ===================
__global__ __launch_bounds__(256, 2) void k_latent(
    const bf16* __restrict__ xb, const bf16* __restrict__ wab,
    const float* __restrict__ kvw, const float* __restrict__ qw,
    bf16* __restrict__ latn)
{
  __shared__ bf16 As[128 * 64], Bs[128 * 64];
  f32x4 acc[4][4];
  const int m0 = blockIdx.x * 128;
  gemm_core(xb, wab, 1024, 1024, 1024, m0, 0, As, Bs, acc);
  const int tid = threadIdx.x, lane = tid & 63, wr = tid >> 7, wc = (tid >> 6) & 1;
  const int fr = lane & 15, fg = lane >> 4;
  const float* nw = wc ? qw : kvw;          // wave's 64 cols == one latent half
  float wv[4];
#pragma unroll
  for (int ni = 0; ni < 4; ni++) wv[ni] = nw[ni * 16 + fr];
#pragma unroll
  for (int mi = 0; mi < 4; mi++) {
    f32x4 ss;
#pragma unroll
    for (int r = 0; r < 4; r++) {
      float s = 0.f;
#pragma unroll
      for (int ni = 0; ni < 4; ni++) { float v = acc[mi][ni][r]; s += v * v; }
      ss[r] = s;
    }
#pragma unroll
    for (int mask = 1; mask < 16; mask <<= 1)
#pragma unroll
      for (int r = 0; r < 4; r++) ss[r] += __shfl_xor(ss[r], mask, 64);
    f32x4 sc;
#pragma unroll
    for (int r = 0; r < 4; r++) sc[r] = rsqrtf(ss[r] * (1.f / 64.f) + 1e-6f);
#pragma unroll
    for (int ni = 0; ni < 4; ni++)
#pragma unroll
      for (int r = 0; r < 4; r++) {
        int row = m0 + wr * 64 + mi * 16 + fg * 4 + r;
        latn[(int64_t)row * 128 + wc * 64 + ni * 16 + fr] = (bf16)(acc[mi][ni][r] * sc[r] * wv[ni]);
      }
  }
}

// ============ KV GEMM: K -> [bh][t][d], V -> transposed [bh][d][t] ============
__global__ __launch_bounds__(256, 2) void k_kv(
    const bf16* __restrict__ latn, const bf16* __restrict__ wkvb,
    bf16* __restrict__ kb, bf16* __restrict__ vtb)
{
  __shared__ bf16 As[128 * 64], Bs[128 * 64];
  f32x4 acc[4][4];
  const int m0 = blockIdx.x * 128, h = blockIdx.y;
  gemm_core(latn, wkvb, 128, 64, 64, m0, h * 128, As, Bs, acc);
  const int tid = threadIdx.x, lane = tid & 63, wr = tid >> 7, wc = (tid >> 6) & 1;
  const int fr = lane & 15, fg = lane >> 4;
#pragma unroll
  for (int mi = 0; mi < 4; mi++)
#pragma unroll
    for (int ni = 0; ni < 4; ni++)
#pragma unroll
      for (int r = 0; r < 4; r++) {
        int m = m0 + wr * 64 + mi * 16 + fg * 4 + r;
        int b = m >> 11, t = m & 2047;
        int c = ni * 16 + fr;
        bf16 v = (bf16)acc[mi][ni][r];
        if (wc == 0) kb [(int64_t)((b * 16 + h) * 2048 + t) * 64 + c] = v;
        else         vtb[(int64_t)((b * 16 + h) * 64 + c) * 2048 + t] = v;
      }
}

// ================= Q GEMM (folds 1/sqrt(D) into Q, exact pow2) =================
__global__ __launch_bounds__(256, 2) void k_q(
    const bf16* __restrict__ latn, const bf16* __restrict__ wqb,
    bf16* __restrict__ qbuf)
{
  __shared__ bf16 As[128 * 64], Bs[128 * 64];
  f32x4 acc[4][4];
  const int m0 = blockIdx.x * 128, n0 = blockIdx.y * 128;
  gemm_core(latn + 64, wqb, 128, 64, 64, m0, n0, As, Bs, acc);
  const int tid = threadIdx.x, lane = tid & 63, wr = tid >> 7, wc = (tid >> 6) & 1;
  const int fr = lane & 15, fg = lane >> 4;
#pragma unroll
  for (int mi = 0; mi < 4; mi++)
#pragma unroll
    for (int ni = 0; ni < 4; ni++)
#pragma unroll
      for (int r = 0; r < 4; r++) {
        int m = m0 + wr * 64 + mi * 16 + fg * 4 + r;
        int b = m >> 11, t = m & 2047;
        int n = n0 + wc * 64 + ni * 16 + fr;
        int hh = n >> 6, d = n & 63;
        qbuf[(int64_t)((b * 16 + hh) * 2048 + t) * 64 + d] = (bf16)(acc[mi][ni][r] * 0.125f);
      }
}

// ========================== flash attention ==========================
// grid (64 bh, 16 q-tiles); 4 waves x 32 q-rows; KV-tile = 128.
// LDS: Vts [64][128] swizzled; KsP union: Ks [128][64] during QK^T, then
// P [128][128] (wave w owns rows 32w..32w+31). All tiles XOR-chunk-swizzled.
__global__ __launch_bounds__(256, 3) void k_attn(
    const bf16* __restrict__ qb, const bf16* __restrict__ kb,
    const bf16* __restrict__ vtb, bf16* __restrict__ yb)
{
  __shared__ bf16 Vts[64 * 128];
  __shared__ bf16 KsP[128 * 128];
  const int bh = blockIdx.x, qt = blockIdx.y;
  const int b = bh >> 4, h = bh & 15;
  const int tid = threadIdx.x, lane = tid & 63, w = tid >> 6;
  const int fr = lane & 15, fg = lane >> 4;
  const int64_t base = (int64_t)bh * (2048 * 64);
  bf16* Ks = KsP;
  bf16* Pw = KsP + w * 32 * 128;
  const int q0 = qt * 128 + w * 32;

  bf16x8 aq[2][2];
#pragma unroll
  for (int mi = 0; mi < 2; mi++)
#pragma unroll
    for (int kk = 0; kk < 2; kk++)
      aq[mi][kk] = *(const bf16x8*)(qb + base + (int64_t)(q0 + mi * 16 + fr) * 64 + kk * 32 + fg * 8);

  f32x4 o[2][4], mAcc[2], lAcc[2];
#pragma unroll
  for (int mi = 0; mi < 2; mi++) {
#pragma unroll
    for (int di = 0; di < 4; di++) o[mi][di] = (f32x4){0.f, 0.f, 0.f, 0.f};
#pragma unroll
    for (int r = 0; r < 4; r++) { mAcc[mi][r] = -__builtin_inff(); lAcc[mi][r] = 0.f; }
  }
  const int r0 = tid >> 3, c0 = (tid & 7) * 8;
  const int cswK = (((tid & 7) ^ (r0 & 7)) * 8);                 // K staging src swizzle
  const int pcV = tid & 15, drB = (tid >> 4) & 7;                // V staging indices
  const int cswV = ((pcV ^ drB) * 8);

  for (int kt = 0; kt < 16; kt++) {
    const int t0 = kt * 128;
#pragma unroll
    for (int p = 0; p < 4; p++) {
      int row = p * 32 + r0;
      gl16(kb + base + (int64_t)(t0 + row) * 64 + cswK, Ks + row * 64 + c0);
    }
#pragma unroll
    for (int p = 0; p < 4; p++) {
      int chunk = p * 256 + tid;
      int dr = chunk >> 4;
      gl16(vtb + base + (int64_t)dr * 2048 + t0 + cswV, Vts + dr * 128 + pcV * 8);
    }
    __syncthreads();
    // ---- S = (Q*scale) @ K^T ----
    f32x4 s[2][8];
#pragma unroll
    for (int mi = 0; mi < 2; mi++)
#pragma unroll
      for (int ni = 0; ni < 8; ni++) s[mi][ni] = (f32x4){0.f, 0.f, 0.f, 0.f};
#pragma unroll
    for (int kk = 0; kk < 2; kk++) {
      bf16x8 bk[8];
#pragma unroll
      for (int ni = 0; ni < 8; ni++)
        bk[ni] = *(const bf16x8*)(Ks + (ni * 16 + fr) * 64 + (((kk * 4 + fg) ^ (fr & 7)) * 8));
#pragma unroll
      for (int mi = 0; mi < 2; mi++)
#pragma unroll
        for (int ni = 0; ni < 8; ni++)
          s[mi][ni] = MFMA16(aq[mi][kk], bk[ni], s[mi][ni]);
    }
    __syncthreads();   // all waves done reading Ks before P overwrites it
    // ---- online softmax (C-layout: row = fg*4+r, col = ni*16+fr) ----
#pragma unroll
    for (int mi = 0; mi < 2; mi++) {
      f32x4 pm;
#pragma unroll
      for (int r = 0; r < 4; r++) {
        float v = s[mi][0][r];
#pragma unroll
        for (int ni = 1; ni < 8; ni++) v = fmaxf(v, s[mi][ni][r]);
        pm[r] = v;
      }
#pragma unroll
      for (int mask = 1; mask < 16; mask <<= 1)
#pragma unroll
        for (int r = 0; r < 4; r++) pm[r] = fmaxf(pm[r], __shfl_xor(pm[r], mask, 64));
      f32x4 alpha, rs;
#pragma unroll
      for (int r = 0; r < 4; r++) {
        float mn = fmaxf(mAcc[mi][r], pm[r]);
        alpha[r] = exp2f((mAcc[mi][r] - mn) * 1.44269504f);
        mAcc[mi][r] = mn; rs[r] = 0.f;
      }
#pragma unroll
      for (int ni = 0; ni < 8; ni++)
#pragma unroll
        for (int r = 0; r < 4; r++) {
          float p = exp2f((s[mi][ni][r] - mAcc[mi][r]) * 1.44269504f);
          rs[r] += p;
          int rp = mi * 16 + fg * 4 + r;
          int c  = ni * 16 + fr;
          Pw[rp * 128 + ((((c >> 3) ^ (rp & 7)) << 3) | (c & 7))] = (bf16)p;
        }
#pragma unroll
      for (int mask = 1; mask < 16; mask <<= 1)
#pragma unroll
        for (int r = 0; r < 4; r++) rs[r] += __shfl_xor(rs[r], mask, 64);
#pragma unroll
      for (int r = 0; r < 4; r++) lAcc[mi][r] = lAcc[mi][r] * alpha[r] + rs[r];
#pragma unroll
      for (int di = 0; di < 4; di++)
#pragma unroll
        for (int r = 0; r < 4; r++) o[mi][di][r] *= alpha[r];
    }
    // ---- O += P @ V  (P wave-private; V pre-transposed) ----
#pragma unroll
    for (int k2 = 0; k2 < 4; k2++) {
      bf16x8 pa[2], vv[4];
#pragma unroll
      for (int mi = 0; mi < 2; mi++)
        pa[mi] = *(const bf16x8*)(Pw + (mi * 16 + fr) * 128 + (((k2 * 4 + fg) ^ (fr & 7)) * 8));
#pragma unroll
      for (int di = 0; di < 4; di++)
        vv[di] = *(const bf16x8*)(Vts + (di * 16 + fr) * 128 + (((k2 * 4 + fg) ^ (fr & 7)) * 8));
#pragma unroll
      for (int mi = 0; mi < 2; mi++)
#pragma unroll
        for (int di = 0; di < 4; di++)
          o[mi][di] = MFMA16(pa[mi], vv[di], o[mi][di]);
    }
    __syncthreads();   // all reads of P/Vts done before next staging
  }
  // ---- epilogue: y[b][t][h*64+d] = O / l ----
#pragma unroll
  for (int mi = 0; mi < 2; mi++)
#pragma unroll
    for (int di = 0; di < 4; di++)
#pragma unroll
      for (int r = 0; r < 4; r++) {
        int t = q0 + mi * 16 + fg * 4 + r;
        float v = o[mi][di][r] / lAcc[mi][r];
        yb[((int64_t)b * 2048 + t) * 1024 + h * 64 + di * 16 + fr] = (bf16)v;
      }
}

// ========================= output projection =========================
__global__ __launch_bounds__(256, 2) void k_proj(
    const bf16* __restrict__ yb, const bf16* __restrict__ wp, float* __restrict__ out)
{
  __shared__ bf16 As[128 * 64], Bs[128 * 64];
  f32x4 acc[4][4];
  const int m0 = blockIdx.x * 128, n0 = blockIdx.y * 128;
  gemm_core(yb, wp, 1024, 1024, 1024, m0, n0, As, Bs, acc);
  const int tid = threadIdx.x, lane = tid & 63, wr = tid >> 7, wc = (tid >> 6) & 1;
  const int fr = lane & 15, fg = lane >> 4;
#pragma unroll
  for (int mi = 0; mi < 4; mi++)
#pragma unroll
    for (int ni = 0; ni < 4; ni++)
#pragma unroll
      for (int r = 0; r < 4; r++) {
        int m = m0 + wr * 64 + mi * 16 + fg * 4 + r;
        int n = n0 + wc * 64 + ni * 16 + fr;
        out[(int64_t)m * 1024 + n] = acc[mi][ni][r];
      }
}

extern "C" void kernel_launch(void* const* d_in, const int* in_sizes, int n_in,
                              void* d_out, int out_size, void* d_ws, size_t ws_size,
                              hipStream_t stream) {
  (void)in_sizes; (void)n_in; (void)out_size; (void)ws_size;
  const float* x     = (const float*)d_in[0];
  const float* wkva  = (const float*)d_in[1];
  const float* wkvb  = (const float*)d_in[2];
  const float* wqa   = (const float*)d_in[3];
  const float* wqb   = (const float*)d_in[4];
  const float* wproj = (const float*)d_in[5];
  const float* kvw   = (const float*)d_in[6];
  const float* qw    = (const float*)d_in[7];
  bf16* ws  = (bf16*)d_ws;
  float* out = (float*)d_out;

  k_convert<<<dim3(9536), dim3(256), 0, stream>>>(x, wkva, wkvb, wqa, wqb, wproj, ws);
  k_latent <<<dim3(64), dim3(256), 0, stream>>>(ws + OFF_XB, ws + OFF_WAB, kvw, qw, ws + OFF_LATN);
  k_kv     <<<dim3(64, 16), dim3(256), 0, stream>>>(ws + OFF_LATN, ws + OFF_WKVB, ws + OFF_K, ws + OFF_VT);
  k_q      <<<dim3(64, 8), dim3(256), 0, stream>>>(ws + OFF_LATN, ws + OFF_WQB, ws + OFF_Q);
  k_attn   <<<dim3(64, 16), dim3(256), 0, stream>>>(ws + OFF_Q, ws + OFF_K, ws + OFF_VT, ws + OFF_Y);
  k_proj   <<<dim3(64, 8), dim3(256), 0, stream>>>(ws + OFF_Y, ws + OFF_WPROJ, out);
}

// Round 3
// 358.048 us; speedup vs baseline: 2.2293x; 2.2293x over previous
//
#include <hip/hip_runtime.h>
#include <stdint.h>

typedef __bf16 bf16;
typedef __bf16 bf16x8 __attribute__((ext_vector_type(8)));
typedef __bf16 bf16x4 __attribute__((ext_vector_type(4)));
typedef float  f32x4  __attribute__((ext_vector_type(4)));

#define MFMA16(a,b,c) __builtin_amdgcn_mfma_f32_16x16x32_bf16((a),(b),(c),0,0,0)

__device__ __forceinline__ void gl16(const bf16* g, bf16* l) {
  __builtin_amdgcn_global_load_lds((const __attribute__((address_space(1))) void*)g,
                                   (__attribute__((address_space(3))) void*)l, 16, 0, 0);
}

// ---- ws layout (bf16 element offsets) ----
#define OFF_XB     0LL
#define OFF_WAB    8388608LL   // [128][1024]: rows 0-63 = w_kv_a, 64-127 = w_q_a
#define OFF_WKVB   8519680LL   // [2048][64]
#define OFF_WQB    8650752LL   // [1024][64]
#define OFF_WPROJ  8716288LL   // [1024][1024]
#define OFF_LATN   9764864LL   // [8192][128] normalized latents (kv | q)
#define OFF_K      10813440LL  // [64 bh][2048 t][64 d]
#define OFF_VT     19202048LL  // [64 bh][64 d][2048 t]  (V transposed)
#define OFF_Q      27590656LL  // [64 bh][2048 t][64 d]  (pre-scaled by 0.125)
#define OFF_Y      35979264LL  // [4 b][2048 t][1024 hd]

// ============================ convert fp32 -> bf16 ============================
__global__ __launch_bounds__(256) void k_convert(
    const float* __restrict__ x, const float* __restrict__ wkva, const float* __restrict__ wkvb,
    const float* __restrict__ wqa, const float* __restrict__ wqb, const float* __restrict__ wproj,
    bf16* __restrict__ ws)
{
  int64_t q = (int64_t)blockIdx.x * 256 + threadIdx.x;   // float4-quad index
  const float* src; bf16* dst;
  if (q < 2097152LL)      { src = x + 4*q;                          dst = ws + OFF_XB + 4*q; }
  else if (q < 2129920LL) { int64_t e = 4*(q - 2097152LL);
                            int row = (int)(e >> 10), col = (int)(e & 1023);
                            src = (row < 64) ? (wkva + ((int64_t)row << 10) + col)
                                             : (wqa + ((int64_t)(row - 64) << 10) + col);
                            dst = ws + OFF_WAB + e; }
  else if (q < 2162688LL) { int64_t j = q - 2129920LL; src = wkvb + 4*j; dst = ws + OFF_WKVB + 4*j; }
  else if (q < 2179072LL) { int64_t j = q - 2162688LL; src = wqb  + 4*j; dst = ws + OFF_WQB  + 4*j; }
  else if (q < 2441216LL) { int64_t j = q - 2179072LL; src = wproj+ 4*j; dst = ws + OFF_WPROJ+ 4*j; }
  else return;
  float4 v = *(const float4*)src;
  bf16x4 o; o.x = (bf16)v.x; o.y = (bf16)v.y; o.z = (bf16)v.z; o.w = (bf16)v.w;
  *(bf16x4*)dst = o;
}

// ================= shared 128x128-tile GEMM mainloop (C = A @ B^T) =================
// LDS tiles are [128 rows][8 chunks of 16B], XOR-swizzled: physical chunk p at
// (row,p) holds logical chunk c = p ^ (row&7). global_load_lds keeps LDS linear
// (phys byte = tid*16); the SOURCE column is pre-swizzled (rule #21).
__device__ __forceinline__ void gemm_core(
    const bf16* __restrict__ A, const bf16* __restrict__ B,
    int lda, int ldb, int K, int m0, int n0,
    bf16* As, bf16* Bs, f32x4 acc[4][4])
{
  const int tid = threadIdx.x, lane = tid & 63;
  const int wr = tid >> 7, wc = (tid >> 6) & 1;
  const int r0 = tid >> 3, c0 = (tid & 7) * 8;
  const int csw = (((tid & 7) ^ (r0 & 7)) * 8);     // swizzled source col (elements)
  const int fr = lane & 15, fg = lane >> 4;
#pragma unroll
  for (int mi = 0; mi < 4; mi++)
#pragma unroll
    for (int ni = 0; ni < 4; ni++) acc[mi][ni] = (f32x4){0.f, 0.f, 0.f, 0.f};
  for (int kt = 0; kt < K; kt += 64) {
#pragma unroll
    for (int p = 0; p < 4; p++) {
      int row = p * 32 + r0;
      gl16(A + (int64_t)(m0 + row) * lda + kt + csw, As + row * 64 + c0);
      gl16(B + (int64_t)(n0 + row) * ldb + kt + csw, Bs + row * 64 + c0);
    }
    __syncthreads();   // drains vmcnt (global_load_lds) + barrier
#pragma unroll
    for (int kk = 0; kk < 2; kk++) {
      bf16x8 af[4], bfr[4];
#pragma unroll
      for (int i = 0; i < 4; i++) {
        af[i]  = *(const bf16x8*)(As + (wr * 64 + i * 16 + fr) * 64 + (((kk * 4 + fg) ^ (fr & 7)) * 8));
        bfr[i] = *(const bf16x8*)(Bs + (wc * 64 + i * 16 + fr) * 64 + (((kk * 4 + fg) ^ (fr & 7)) * 8));
      }
#pragma unroll
      for (int mi = 0; mi < 4; mi++)
#pragma unroll
        for (int ni = 0; ni < 4; ni++)
          acc[mi][ni] = MFMA16(af[mi], bfr[ni], acc[mi][ni]);
    }
    __syncthreads();
  }
}

// =================== latent GEMM + fused RMSNorm epilogue ===================
__global__ __launch_bounds__(256, 2) void k_latent(
    const bf16* __restrict__ xb, const bf16* __restrict__ wab,
    const float* __restrict__ kvw, const float* __restrict__ qw,
    bf16* __restrict__ latn)
{
  __shared__ bf16 As[128 * 64], Bs[128 * 64];
  f32x4 acc[4][4];
  const int m0 = blockIdx.x * 128;
  gemm_core(xb, wab, 1024, 1024, 1024, m0, 0, As, Bs, acc);
  const int tid = threadIdx.x, lane = tid & 63, wr = tid >> 7, wc = (tid >> 6) & 1;
  const int fr = lane & 15, fg = lane >> 4;
  const float* nw = wc ? qw : kvw;          // wave's 64 cols == one latent half
  float wv[4];
#pragma unroll
  for (int ni = 0; ni < 4; ni++) wv[ni] = nw[ni * 16 + fr];
#pragma unroll
  for (int mi = 0; mi < 4; mi++) {
    f32x4 ss;
#pragma unroll
    for (int r = 0; r < 4; r++) {
      float s = 0.f;
#pragma unroll
      for (int ni = 0; ni < 4; ni++) { float v = acc[mi][ni][r]; s += v * v; }
      ss[r] = s;
    }
#pragma unroll
    for (int mask = 1; mask < 16; mask <<= 1)
#pragma unroll
      for (int r = 0; r < 4; r++) ss[r] += __shfl_xor(ss[r], mask, 64);
    f32x4 sc;
#pragma unroll
    for (int r = 0; r < 4; r++) sc[r] = rsqrtf(ss[r] * (1.f / 64.f) + 1e-6f);
#pragma unroll
    for (int ni = 0; ni < 4; ni++)
#pragma unroll
      for (int r = 0; r < 4; r++) {
        int row = m0 + wr * 64 + mi * 16 + fg * 4 + r;
        latn[(int64_t)row * 128 + wc * 64 + ni * 16 + fr] = (bf16)(acc[mi][ni][r] * sc[r] * wv[ni]);
      }
  }
}

// ============ KV GEMM: K -> [bh][t][d], V -> transposed [bh][d][t] ============
__global__ __launch_bounds__(256, 2) void k_kv(
    const bf16* __restrict__ latn, const bf16* __restrict__ wkvb,
    bf16* __restrict__ kb, bf16* __restrict__ vtb)
{
  __shared__ bf16 As[128 * 64], Bs[128 * 64];
  f32x4 acc[4][4];
  const int m0 = blockIdx.x * 128, h = blockIdx.y;
  gemm_core(latn, wkvb, 128, 64, 64, m0, h * 128, As, Bs, acc);
  const int tid = threadIdx.x, lane = tid & 63, wr = tid >> 7, wc = (tid >> 6) & 1;
  const int fr = lane & 15, fg = lane >> 4;
#pragma unroll
  for (int mi = 0; mi < 4; mi++)
#pragma unroll
    for (int ni = 0; ni < 4; ni++)
#pragma unroll
      for (int r = 0; r < 4; r++) {
        int m = m0 + wr * 64 + mi * 16 + fg * 4 + r;
        int b = m >> 11, t = m & 2047;
        int c = ni * 16 + fr;
        bf16 v = (bf16)acc[mi][ni][r];
        if (wc == 0) kb [(int64_t)((b * 16 + h) * 2048 + t) * 64 + c] = v;
        else         vtb[(int64_t)((b * 16 + h) * 64 + c) * 2048 + t] = v;
      }
}

// ================= Q GEMM (folds 1/sqrt(D) into Q, exact pow2) =================
__global__ __launch_bounds__(256, 2) void k_q(
    const bf16* __restrict__ latn, const bf16* __restrict__ wqb,
    bf16* __restrict__ qbuf)
{
  __shared__ bf16 As[128 * 64], Bs[128 * 64];
  f32x4 acc[4][4];
  const int m0 = blockIdx.x * 128, n0 = blockIdx.y * 128;
  gemm_core(latn + 64, wqb, 128, 64, 64, m0, n0, As, Bs, acc);
  const int tid = threadIdx.x, lane = tid & 63, wr = tid >> 7, wc = (tid >> 6) & 1;
  const int fr = lane & 15, fg = lane >> 4;
#pragma unroll
  for (int mi = 0; mi < 4; mi++)
#pragma unroll
    for (int ni = 0; ni < 4; ni++)
#pragma unroll
      for (int r = 0; r < 4; r++) {
        int m = m0 + wr * 64 + mi * 16 + fg * 4 + r;
        int b = m >> 11, t = m & 2047;
        int n = n0 + wc * 64 + ni * 16 + fr;
        int hh = n >> 6, d = n & 63;
        qbuf[(int64_t)((b * 16 + hh) * 2048 + t) * 64 + d] = (bf16)(acc[mi][ni][r] * 0.125f);
      }
}

// ========================== flash attention ==========================
// grid (64 bh, 16 q-tiles); 4 waves x 32 q-rows; KV-tile = 128.
// LDS: Vts [64][128] swizzled; KsP union: Ks [128][64] during QK^T, then
// P [128][128] (wave w owns rows 32w..32w+31). All tiles XOR-chunk-swizzled.
// launch_bounds (256,2): VGPR cap 256 — attn needs ~160 live VGPRs; capping
// tighter (R2's (256,3) -> 84 VGPR) spills accumulators to scratch (652MB
// FETCH). LDS=48K still gives 3 blocks/CU when compiler lands at <=128 VGPR.
__global__ __launch_bounds__(256, 2) void k_attn(
    const bf16* __restrict__ qb, const bf16* __restrict__ kb,
    const bf16* __restrict__ vtb, bf16* __restrict__ yb)
{
  __shared__ bf16 Vts[64 * 128];
  __shared__ bf16 KsP[128 * 128];
  const int bh = blockIdx.x, qt = blockIdx.y;
  const int b = bh >> 4, h = bh & 15;
  const int tid = threadIdx.x, lane = tid & 63, w = tid >> 6;
  const int fr = lane & 15, fg = lane >> 4;
  const int64_t base = (int64_t)bh * (2048 * 64);
  bf16* Ks = KsP;
  bf16* Pw = KsP + w * 32 * 128;
  const int q0 = qt * 128 + w * 32;

  bf16x8 aq[2][2];
#pragma unroll
  for (int mi = 0; mi < 2; mi++)
#pragma unroll
    for (int kk = 0; kk < 2; kk++)
      aq[mi][kk] = *(const bf16x8*)(qb + base + (int64_t)(q0 + mi * 16 + fr) * 64 + kk * 32 + fg * 8);

  f32x4 o[2][4], mAcc[2], lAcc[2];
#pragma unroll
  for (int mi = 0; mi < 2; mi++) {
#pragma unroll
    for (int di = 0; di < 4; di++) o[mi][di] = (f32x4){0.f, 0.f, 0.f, 0.f};
#pragma unroll
    for (int r = 0; r < 4; r++) { mAcc[mi][r] = -__builtin_inff(); lAcc[mi][r] = 0.f; }
  }
  const int r0 = tid >> 3, c0 = (tid & 7) * 8;
  const int cswK = (((tid & 7) ^ (r0 & 7)) * 8);                 // K staging src swizzle
  const int pcV = tid & 15, drB = (tid >> 4) & 7;                // V staging indices
  const int cswV = ((pcV ^ drB) * 8);

  for (int kt = 0; kt < 16; kt++) {
    const int t0 = kt * 128;
#pragma unroll
    for (int p = 0; p < 4; p++) {
      int row = p * 32 + r0;
      gl16(kb + base + (int64_t)(t0 + row) * 64 + cswK, Ks + row * 64 + c0);
    }
#pragma unroll
    for (int p = 0; p < 4; p++) {
      int chunk = p * 256 + tid;
      int dr = chunk >> 4;
      gl16(vtb + base + (int64_t)dr * 2048 + t0 + cswV, Vts + dr * 128 + pcV * 8);
    }
    __syncthreads();
    // ---- S = (Q*scale) @ K^T ----
    f32x4 s[2][8];
#pragma unroll
    for (int mi = 0; mi < 2; mi++)
#pragma unroll
      for (int ni = 0; ni < 8; ni++) s[mi][ni] = (f32x4){0.f, 0.f, 0.f, 0.f};
#pragma unroll
    for (int kk = 0; kk < 2; kk++) {
      bf16x8 bk[8];
#pragma unroll
      for (int ni = 0; ni < 8; ni++)
        bk[ni] = *(const bf16x8*)(Ks + (ni * 16 + fr) * 64 + (((kk * 4 + fg) ^ (fr & 7)) * 8));
#pragma unroll
      for (int mi = 0; mi < 2; mi++)
#pragma unroll
        for (int ni = 0; ni < 8; ni++)
          s[mi][ni] = MFMA16(aq[mi][kk], bk[ni], s[mi][ni]);
    }
    __syncthreads();   // all waves done reading Ks before P overwrites it
    // ---- online softmax (C-layout: row = fg*4+r, col = ni*16+fr) ----
#pragma unroll
    for (int mi = 0; mi < 2; mi++) {
      f32x4 pm;
#pragma unroll
      for (int r = 0; r < 4; r++) {
        float v = s[mi][0][r];
#pragma unroll
        for (int ni = 1; ni < 8; ni++) v = fmaxf(v, s[mi][ni][r]);
        pm[r] = v;
      }
#pragma unroll
      for (int mask = 1; mask < 16; mask <<= 1)
#pragma unroll
        for (int r = 0; r < 4; r++) pm[r] = fmaxf(pm[r], __shfl_xor(pm[r], mask, 64));
      f32x4 alpha, rs;
#pragma unroll
      for (int r = 0; r < 4; r++) {
        float mn = fmaxf(mAcc[mi][r], pm[r]);
        alpha[r] = exp2f((mAcc[mi][r] - mn) * 1.44269504f);
        mAcc[mi][r] = mn; rs[r] = 0.f;
      }
#pragma unroll
      for (int ni = 0; ni < 8; ni++)
#pragma unroll
        for (int r = 0; r < 4; r++) {
          float p = exp2f((s[mi][ni][r] - mAcc[mi][r]) * 1.44269504f);
          rs[r] += p;
          int rp = mi * 16 + fg * 4 + r;
          int c  = ni * 16 + fr;
          Pw[rp * 128 + ((((c >> 3) ^ (rp & 7)) << 3) | (c & 7))] = (bf16)p;
        }
#pragma unroll
      for (int mask = 1; mask < 16; mask <<= 1)
#pragma unroll
        for (int r = 0; r < 4; r++) rs[r] += __shfl_xor(rs[r], mask, 64);
#pragma unroll
      for (int r = 0; r < 4; r++) lAcc[mi][r] = lAcc[mi][r] * alpha[r] + rs[r];
#pragma unroll
      for (int di = 0; di < 4; di++)
#pragma unroll
        for (int r = 0; r < 4; r++) o[mi][di][r] *= alpha[r];
    }
    // ---- O += P @ V  (P wave-private; V pre-transposed) ----
#pragma unroll
    for (int k2 = 0; k2 < 4; k2++) {
      bf16x8 pa[2], vv[4];
#pragma unroll
      for (int mi = 0; mi < 2; mi++)
        pa[mi] = *(const bf16x8*)(Pw + (mi * 16 + fr) * 128 + (((k2 * 4 + fg) ^ (fr & 7)) * 8));
#pragma unroll
      for (int di = 0; di < 4; di++)
        vv[di] = *(const bf16x8*)(Vts + (di * 16 + fr) * 128 + (((k2 * 4 + fg) ^ (fr & 7)) * 8));
#pragma unroll
      for (int mi = 0; mi < 2; mi++)
#pragma unroll
        for (int di = 0; di < 4; di++)
          o[mi][di] = MFMA16(pa[mi], vv[di], o[mi][di]);
    }
    __syncthreads();   // all reads of P/Vts done before next staging
  }
  // ---- epilogue: y[b][t][h*64+d] = O / l ----
#pragma unroll
  for (int mi = 0; mi < 2; mi++)
#pragma unroll
    for (int di = 0; di < 4; di++)
#pragma unroll
      for (int r = 0; r < 4; r++) {
        int t = q0 + mi * 16 + fg * 4 + r;
        float v = o[mi][di][r] / lAcc[mi][r];
        yb[((int64_t)b * 2048 + t) * 1024 + h * 64 + di * 16 + fr] = (bf16)v;
      }
}

// ========================= output projection =========================
__global__ __launch_bounds__(256, 2) void k_proj(
    const bf16* __restrict__ yb, const bf16* __restrict__ wp, float* __restrict__ out)
{
  __shared__ bf16 As[128 * 64], Bs[128 * 64];
  f32x4 acc[4][4];
  const int m0 = blockIdx.x * 128, n0 = blockIdx.y * 128;
  gemm_core(yb, wp, 1024, 1024, 1024, m0, n0, As, Bs, acc);
  const int tid = threadIdx.x, lane = tid & 63, wr = tid >> 7, wc = (tid >> 6) & 1;
  const int fr = lane & 15, fg = lane >> 4;
#pragma unroll
  for (int mi = 0; mi < 4; mi++)
#pragma unroll
    for (int ni = 0; ni < 4; ni++)
#pragma unroll
      for (int r = 0; r < 4; r++) {
        int m = m0 + wr * 64 + mi * 16 + fg * 4 + r;
        int n = n0 + wc * 64 + ni * 16 + fr;
        out[(int64_t)m * 1024 + n] = acc[mi][ni][r];
      }
}

extern "C" void kernel_launch(void* const* d_in, const int* in_sizes, int n_in,
                              void* d_out, int out_size, void* d_ws, size_t ws_size,
                              hipStream_t stream) {
  (void)in_sizes; (void)n_in; (void)out_size; (void)ws_size;
  const float* x     = (const float*)d_in[0];
  const float* wkva  = (const float*)d_in[1];
  const float* wkvb  = (const float*)d_in[2];
  const float* wqa   = (const float*)d_in[3];
  const float* wqb   = (const float*)d_in[4];
  const float* wproj = (const float*)d_in[5];
  const float* kvw   = (const float*)d_in[6];
  const float* qw    = (const float*)d_in[7];
  bf16* ws  = (bf16*)d_ws;
  float* out = (float*)d_out;

  k_convert<<<dim3(9536), dim3(256), 0, stream>>>(x, wkva, wkvb, wqa, wqb, wproj, ws);
  k_latent <<<dim3(64), dim3(256), 0, stream>>>(ws + OFF_XB, ws + OFF_WAB, kvw, qw, ws + OFF_LATN);
  k_kv     <<<dim3(64, 16), dim3(256), 0, stream>>>(ws + OFF_LATN, ws + OFF_WKVB, ws + OFF_K, ws + OFF_VT);
  k_q      <<<dim3(64, 8), dim3(256), 0, stream>>>(ws + OFF_LATN, ws + OFF_WQB, ws + OFF_Q);
  k_attn   <<<dim3(64, 16), dim3(256), 0, stream>>>(ws + OFF_Q, ws + OFF_K, ws + OFF_VT, ws + OFF_Y);
  k_proj   <<<dim3(64, 8), dim3(256), 0, stream>>>(ws + OFF_Y, ws + OFF_WPROJ, out);
}

// Round 4
// 304.582 us; speedup vs baseline: 2.6206x; 1.1755x over previous
//
#include <hip/hip_runtime.h>
#include <stdint.h>

typedef __bf16 bf16;
typedef __bf16 bf16x8 __attribute__((ext_vector_type(8)));
typedef __bf16 bf16x4 __attribute__((ext_vector_type(4)));
typedef float  f32x4  __attribute__((ext_vector_type(4)));

#define MFMA16(a,b,c) __builtin_amdgcn_mfma_f32_16x16x32_bf16((a),(b),(c),0,0,0)
#define LOG2E 1.44269504f

__device__ __forceinline__ void gl16(const bf16* g, bf16* l) {
  __builtin_amdgcn_global_load_lds((const __attribute__((address_space(1))) void*)g,
                                   (__attribute__((address_space(3))) void*)l, 16, 0, 0);
}

// ---- ws layout (bf16 element offsets) ----
#define OFF_XB     0LL
#define OFF_WAB    8388608LL   // [128][1024]: rows 0-63 = w_kv_a, 64-127 = w_q_a
#define OFF_WKVB   8519680LL   // [2048][64]
#define OFF_WQB    8650752LL   // [1024][64]
#define OFF_WPROJ  8716288LL   // [1024][1024]
#define OFF_LATN   9764864LL   // [8192][128] normalized latents (kv | q)
#define OFF_K      10813440LL  // [64 bh][2048 t][64 d]
#define OFF_VT     19202048LL  // [64 bh][64 d][2048 t]  (V transposed)
#define OFF_Q      27590656LL  // [64 bh][2048 t][64 d]  (pre-scaled by 0.125)
#define OFF_Y      35979264LL  // [4 b][2048 t][1024 hd]

// ============================ convert fp32 -> bf16 ============================
__global__ __launch_bounds__(256) void k_convert(
    const float* __restrict__ x, const float* __restrict__ wkva, const float* __restrict__ wkvb,
    const float* __restrict__ wqa, const float* __restrict__ wqb, const float* __restrict__ wproj,
    bf16* __restrict__ ws)
{
  int64_t q = (int64_t)blockIdx.x * 256 + threadIdx.x;   // float4-quad index
  const float* src; bf16* dst;
  if (q < 2097152LL)      { src = x + 4*q;                          dst = ws + OFF_XB + 4*q; }
  else if (q < 2129920LL) { int64_t e = 4*(q - 2097152LL);
                            int row = (int)(e >> 10), col = (int)(e & 1023);
                            src = (row < 64) ? (wkva + ((int64_t)row << 10) + col)
                                             : (wqa + ((int64_t)(row - 64) << 10) + col);
                            dst = ws + OFF_WAB + e; }
  else if (q < 2162688LL) { int64_t j = q - 2129920LL; src = wkvb + 4*j; dst = ws + OFF_WKVB + 4*j; }
  else if (q < 2179072LL) { int64_t j = q - 2162688LL; src = wqb  + 4*j; dst = ws + OFF_WQB  + 4*j; }
  else if (q < 2441216LL) { int64_t j = q - 2179072LL; src = wproj+ 4*j; dst = ws + OFF_WPROJ+ 4*j; }
  else return;
  float4 v = *(const float4*)src;
  bf16x4 o; o.x = (bf16)v.x; o.y = (bf16)v.y; o.z = (bf16)v.z; o.w = (bf16)v.w;
  *(bf16x4*)dst = o;
}

// ================= shared 128x128-tile GEMM mainloop (C = A @ B^T) =================
// LDS tiles are [128 rows][8 chunks of 16B], XOR-swizzled: physical chunk p at
// (row,p) holds logical chunk c = p ^ (row&7). global_load_lds keeps LDS linear
// (phys byte = tid*16); the SOURCE column is pre-swizzled (rule #21).
__device__ __forceinline__ void gemm_core(
    const bf16* __restrict__ A, const bf16* __restrict__ B,
    int lda, int ldb, int K, int m0, int n0,
    bf16* As, bf16* Bs, f32x4 acc[4][4])
{
  const int tid = threadIdx.x, lane = tid & 63;
  const int wr = tid >> 7, wc = (tid >> 6) & 1;
  const int r0 = tid >> 3, c0 = (tid & 7) * 8;
  const int csw = (((tid & 7) ^ (r0 & 7)) * 8);     // swizzled source col (elements)
  const int fr = lane & 15, fg = lane >> 4;
#pragma unroll
  for (int mi = 0; mi < 4; mi++)
#pragma unroll
    for (int ni = 0; ni < 4; ni++) acc[mi][ni] = (f32x4){0.f, 0.f, 0.f, 0.f};
  for (int kt = 0; kt < K; kt += 64) {
#pragma unroll
    for (int p = 0; p < 4; p++) {
      int row = p * 32 + r0;
      gl16(A + (int64_t)(m0 + row) * lda + kt + csw, As + row * 64 + c0);
      gl16(B + (int64_t)(n0 + row) * ldb + kt + csw, Bs + row * 64 + c0);
    }
    __syncthreads();   // drains vmcnt (global_load_lds) + barrier
#pragma unroll
    for (int kk = 0; kk < 2; kk++) {
      bf16x8 af[4], bfr[4];
#pragma unroll
      for (int i = 0; i < 4; i++) {
        af[i]  = *(const bf16x8*)(As + (wr * 64 + i * 16 + fr) * 64 + (((kk * 4 + fg) ^ (fr & 7)) * 8));
        bfr[i] = *(const bf16x8*)(Bs + (wc * 64 + i * 16 + fr) * 64 + (((kk * 4 + fg) ^ (fr & 7)) * 8));
      }
#pragma unroll
      for (int mi = 0; mi < 4; mi++)
#pragma unroll
        for (int ni = 0; ni < 4; ni++)
          acc[mi][ni] = MFMA16(af[mi], bfr[ni], acc[mi][ni]);
    }
    __syncthreads();
  }
}

// =================== latent GEMM + fused RMSNorm epilogue ===================
__global__ __launch_bounds__(256, 2) void k_latent(
    const bf16* __restrict__ xb, const bf16* __restrict__ wab,
    const float* __restrict__ kvw, const float* __restrict__ qw,
    bf16* __restrict__ latn)
{
  __shared__ bf16 As[128 * 64], Bs[128 * 64];
  f32x4 acc[4][4];
  const int m0 = blockIdx.x * 128;
  gemm_core(xb, wab, 1024, 1024, 1024, m0, 0, As, Bs, acc);
  const int tid = threadIdx.x, lane = tid & 63, wr = tid >> 7, wc = (tid >> 6) & 1;
  const int fr = lane & 15, fg = lane >> 4;
  const float* nw = wc ? qw : kvw;          // wave's 64 cols == one latent half
  float wv[4];
#pragma unroll
  for (int ni = 0; ni < 4; ni++) wv[ni] = nw[ni * 16 + fr];
#pragma unroll
  for (int mi = 0; mi < 4; mi++) {
    f32x4 ss;
#pragma unroll
    for (int r = 0; r < 4; r++) {
      float s = 0.f;
#pragma unroll
      for (int ni = 0; ni < 4; ni++) { float v = acc[mi][ni][r]; s += v * v; }
      ss[r] = s;
    }
#pragma unroll
    for (int mask = 1; mask < 16; mask <<= 1)
#pragma unroll
      for (int r = 0; r < 4; r++) ss[r] += __shfl_xor(ss[r], mask, 64);
    f32x4 sc;
#pragma unroll
    for (int r = 0; r < 4; r++) sc[r] = rsqrtf(ss[r] * (1.f / 64.f) + 1e-6f);
#pragma unroll
    for (int ni = 0; ni < 4; ni++)
#pragma unroll
      for (int r = 0; r < 4; r++) {
        int row = m0 + wr * 64 + mi * 16 + fg * 4 + r;
        latn[(int64_t)row * 128 + wc * 64 + ni * 16 + fr] = (bf16)(acc[mi][ni][r] * sc[r] * wv[ni]);
      }
  }
}

// ============ KV GEMM: K -> [bh][t][d], V -> transposed [bh][d][t] ============
__global__ __launch_bounds__(256, 2) void k_kv(
    const bf16* __restrict__ latn, const bf16* __restrict__ wkvb,
    bf16* __restrict__ kb, bf16* __restrict__ vtb)
{
  __shared__ bf16 As[128 * 64], Bs[128 * 64];
  f32x4 acc[4][4];
  const int m0 = blockIdx.x * 128, h = blockIdx.y;
  gemm_core(latn, wkvb, 128, 64, 64, m0, h * 128, As, Bs, acc);
  const int tid = threadIdx.x, lane = tid & 63, wr = tid >> 7, wc = (tid >> 6) & 1;
  const int fr = lane & 15, fg = lane >> 4;
#pragma unroll
  for (int mi = 0; mi < 4; mi++)
#pragma unroll
    for (int ni = 0; ni < 4; ni++)
#pragma unroll
      for (int r = 0; r < 4; r++) {
        int m = m0 + wr * 64 + mi * 16 + fg * 4 + r;
        int b = m >> 11, t = m & 2047;
        int c = ni * 16 + fr;
        bf16 v = (bf16)acc[mi][ni][r];
        if (wc == 0) kb [(int64_t)((b * 16 + h) * 2048 + t) * 64 + c] = v;
        else         vtb[(int64_t)((b * 16 + h) * 64 + c) * 2048 + t] = v;
      }
}

// ================= Q GEMM (folds 1/sqrt(D) into Q, exact pow2) =================
__global__ __launch_bounds__(256, 2) void k_q(
    const bf16* __restrict__ latn, const bf16* __restrict__ wqb,
    bf16* __restrict__ qbuf)
{
  __shared__ bf16 As[128 * 64], Bs[128 * 64];
  f32x4 acc[4][4];
  const int m0 = blockIdx.x * 128, n0 = blockIdx.y * 128;
  gemm_core(latn + 64, wqb, 128, 64, 64, m0, n0, As, Bs, acc);
  const int tid = threadIdx.x, lane = tid & 63, wr = tid >> 7, wc = (tid >> 6) & 1;
  const int fr = lane & 15, fg = lane >> 4;
#pragma unroll
  for (int mi = 0; mi < 4; mi++)
#pragma unroll
    for (int ni = 0; ni < 4; ni++)
#pragma unroll
      for (int r = 0; r < 4; r++) {
        int m = m0 + wr * 64 + mi * 16 + fg * 4 + r;
        int b = m >> 11, t = m & 2047;
        int n = n0 + wc * 64 + ni * 16 + fr;
        int hh = n >> 6, d = n & 63;
        qbuf[(int64_t)((b * 16 + hh) * 2048 + t) * 64 + d] = (bf16)(acc[mi][ni][r] * 0.125f);
      }
}

// ========================== flash attention ==========================
// grid (64 bh, 16 q-tiles); 4 waves x 32 q-rows; KV-tile = 128.
// SWAPPED QK^T (T12 idea): sT = MFMA16(K_frag, Q_frag) gives lane (fr,fg),
// reg r the score S[kv = ni*16+fg*4+r][q = mi*16+fr] — each lane owns 32
// scores of ONE q-row -> in-lane row reduce + 2 shfl (xor16/32); P written
// as bf16x4 (4 consecutive kv) -> 16 ds_write_b64 instead of 64 b16 stores.
// Stats (m,l) live per-lane scalar in S-layout; alpha/l broadcast to the
// O-layout (q = mi*16+fg*4+r) with 4 shuffles per mi.
__global__ __launch_bounds__(256, 2) void k_attn(
    const bf16* __restrict__ qb, const bf16* __restrict__ kb,
    const bf16* __restrict__ vtb, bf16* __restrict__ yb)
{
  __shared__ bf16 Vts[64 * 128];
  __shared__ bf16 KsP[128 * 128];
  const int bh = blockIdx.x, qt = blockIdx.y;
  const int b = bh >> 4, h = bh & 15;
  const int tid = threadIdx.x, lane = tid & 63, w = tid >> 6;
  const int fr = lane & 15, fg = lane >> 4;
  const int fg4 = fg * 4;
  const int64_t base = (int64_t)bh * (2048 * 64);
  bf16* Ks = KsP;
  bf16* Pw = KsP + w * 32 * 128;
  const int q0 = qt * 128 + w * 32;

  bf16x8 aq[2][2];
#pragma unroll
  for (int mi = 0; mi < 2; mi++)
#pragma unroll
    for (int kk = 0; kk < 2; kk++)
      aq[mi][kk] = *(const bf16x8*)(qb + base + (int64_t)(q0 + mi * 16 + fr) * 64 + kk * 32 + fg * 8);

  f32x4 o[2][4];
  float mS[2], lS[2];
#pragma unroll
  for (int mi = 0; mi < 2; mi++) {
#pragma unroll
    for (int di = 0; di < 4; di++) o[mi][di] = (f32x4){0.f, 0.f, 0.f, 0.f};
    mS[mi] = -__builtin_inff(); lS[mi] = 0.f;
  }
  const int r0 = tid >> 3, c0 = (tid & 7) * 8;
  const int cswK = (((tid & 7) ^ (r0 & 7)) * 8);                 // K staging src swizzle
  const int pcV = tid & 15, drB = (tid >> 4) & 7;                // V staging indices
  const int cswV = ((pcV ^ drB) * 8);

  for (int kt = 0; kt < 16; kt++) {
    const int t0 = kt * 128;
#pragma unroll
    for (int p = 0; p < 4; p++) {
      int row = p * 32 + r0;
      gl16(kb + base + (int64_t)(t0 + row) * 64 + cswK, Ks + row * 64 + c0);
    }
#pragma unroll
    for (int p = 0; p < 4; p++) {
      int chunk = p * 256 + tid;
      int dr = chunk >> 4;
      gl16(vtb + base + (int64_t)dr * 2048 + t0 + cswV, Vts + dr * 128 + pcV * 8);
    }
    __syncthreads();
    // ---- S^T = K @ Q^T : sT[mi][ni] has S[kv=ni*16+fg*4+r][q=mi*16+fr] ----
    f32x4 sT[2][8];
#pragma unroll
    for (int mi = 0; mi < 2; mi++)
#pragma unroll
      for (int ni = 0; ni < 8; ni++) sT[mi][ni] = (f32x4){0.f, 0.f, 0.f, 0.f};
#pragma unroll
    for (int kk = 0; kk < 2; kk++) {
      bf16x8 bk[8];
#pragma unroll
      for (int ni = 0; ni < 8; ni++)
        bk[ni] = *(const bf16x8*)(Ks + (ni * 16 + fr) * 64 + (((kk * 4 + fg) ^ (fr & 7)) * 8));
#pragma unroll
      for (int mi = 0; mi < 2; mi++)
#pragma unroll
        for (int ni = 0; ni < 8; ni++)
          sT[mi][ni] = MFMA16(bk[ni], aq[mi][kk], sT[mi][ni]);
    }
    __syncthreads();   // all waves done reading Ks before P overwrites it
    // ---- online softmax, per-lane row-local ----
#pragma unroll
    for (int mi = 0; mi < 2; mi++) {
      float pm = sT[mi][0][0];
#pragma unroll
      for (int ni = 0; ni < 8; ni++)
#pragma unroll
        for (int r = 0; r < 4; r++) pm = fmaxf(pm, sT[mi][ni][r]);
      pm = fmaxf(pm, __shfl_xor(pm, 16, 64));
      pm = fmaxf(pm, __shfl_xor(pm, 32, 64));
      float mn = fmaxf(mS[mi], pm);
      float alphaS = exp2f((mS[mi] - mn) * LOG2E);
      mS[mi] = mn;
      const float mnL = mn * LOG2E;
      float rs = 0.f;
      bf16* pwr = Pw + (mi * 16 + fr) * 128 + (fg & 1) * 4;
      const int cxor = fr & 7;
#pragma unroll
      for (int ni = 0; ni < 8; ni++) {
        float p0 = exp2f(fmaf(sT[mi][ni][0], LOG2E, -mnL));
        float p1 = exp2f(fmaf(sT[mi][ni][1], LOG2E, -mnL));
        float p2 = exp2f(fmaf(sT[mi][ni][2], LOG2E, -mnL));
        float p3 = exp2f(fmaf(sT[mi][ni][3], LOG2E, -mnL));
        rs += (p0 + p1) + (p2 + p3);
        bf16x4 pk4;
        pk4[0] = (bf16)p0; pk4[1] = (bf16)p1; pk4[2] = (bf16)p2; pk4[3] = (bf16)p3;
        *(bf16x4*)(pwr + (((ni * 2 + (fg >> 1)) ^ cxor) << 3)) = pk4;
      }
      rs += __shfl_xor(rs, 16, 64);
      rs += __shfl_xor(rs, 32, 64);
      lS[mi] = lS[mi] * alphaS + rs;
      float aO[4];
#pragma unroll
      for (int r = 0; r < 4; r++) aO[r] = __shfl(alphaS, fg4 + r, 64);
#pragma unroll
      for (int di = 0; di < 4; di++)
#pragma unroll
        for (int r = 0; r < 4; r++) o[mi][di][r] *= aO[r];
    }
    __syncthreads();   // P fully written before PV reads (wave-private, but staging next)
    // ---- O += P @ V  (P wave-private; V pre-transposed) ----
#pragma unroll
    for (int k2 = 0; k2 < 4; k2++) {
      bf16x8 pa[2], vv[4];
#pragma unroll
      for (int mi = 0; mi < 2; mi++)
        pa[mi] = *(const bf16x8*)(Pw + (mi * 16 + fr) * 128 + (((k2 * 4 + fg) ^ (fr & 7)) * 8));
#pragma unroll
      for (int di = 0; di < 4; di++)
        vv[di] = *(const bf16x8*)(Vts + (di * 16 + fr) * 128 + (((k2 * 4 + fg) ^ (fr & 7)) * 8));
#pragma unroll
      for (int mi = 0; mi < 2; mi++)
#pragma unroll
        for (int di = 0; di < 4; di++)
          o[mi][di] = MFMA16(pa[mi], vv[di], o[mi][di]);
    }
    __syncthreads();   // all reads of P/Vts done before next staging
  }
  // ---- epilogue: y[b][t][h*64+d] = O / l (l broadcast S-layout -> O-layout) ----
#pragma unroll
  for (int mi = 0; mi < 2; mi++) {
    float lO[4];
#pragma unroll
    for (int r = 0; r < 4; r++) lO[r] = __shfl(lS[mi], fg4 + r, 64);
#pragma unroll
    for (int di = 0; di < 4; di++)
#pragma unroll
      for (int r = 0; r < 4; r++) {
        int t = q0 + mi * 16 + fg * 4 + r;
        float v = o[mi][di][r] / lO[r];
        yb[((int64_t)b * 2048 + t) * 1024 + h * 64 + di * 16 + fr] = (bf16)v;
      }
  }
}

// ========================= output projection =========================
__global__ __launch_bounds__(256, 2) void k_proj(
    const bf16* __restrict__ yb, const bf16* __restrict__ wp, float* __restrict__ out)
{
  __shared__ bf16 As[128 * 64], Bs[128 * 64];
  f32x4 acc[4][4];
  const int m0 = blockIdx.x * 128, n0 = blockIdx.y * 128;
  gemm_core(yb, wp, 1024, 1024, 1024, m0, n0, As, Bs, acc);
  const int tid = threadIdx.x, lane = tid & 63, wr = tid >> 7, wc = (tid >> 6) & 1;
  const int fr = lane & 15, fg = lane >> 4;
#pragma unroll
  for (int mi = 0; mi < 4; mi++)
#pragma unroll
    for (int ni = 0; ni < 4; ni++)
#pragma unroll
      for (int r = 0; r < 4; r++) {
        int m = m0 + wr * 64 + mi * 16 + fg * 4 + r;
        int n = n0 + wc * 64 + ni * 16 + fr;
        out[(int64_t)m * 1024 + n] = acc[mi][ni][r];
      }
}

extern "C" void kernel_launch(void* const* d_in, const int* in_sizes, int n_in,
                              void* d_out, int out_size, void* d_ws, size_t ws_size,
                              hipStream_t stream) {
  (void)in_sizes; (void)n_in; (void)out_size; (void)ws_size;
  const float* x     = (const float*)d_in[0];
  const float* wkva  = (const float*)d_in[1];
  const float* wkvb  = (const float*)d_in[2];
  const float* wqa   = (const float*)d_in[3];
  const float* wqb   = (const float*)d_in[4];
  const float* wproj = (const float*)d_in[5];
  const float* kvw   = (const float*)d_in[6];
  const float* qw    = (const float*)d_in[7];
  bf16* ws  = (bf16*)d_ws;
  float* out = (float*)d_out;

  k_convert<<<dim3(9536), dim3(256), 0, stream>>>(x, wkva, wkvb, wqa, wqb, wproj, ws);
  k_latent <<<dim3(64), dim3(256), 0, stream>>>(ws + OFF_XB, ws + OFF_WAB, kvw, qw, ws + OFF_LATN);
  k_kv     <<<dim3(64, 16), dim3(256), 0, stream>>>(ws + OFF_LATN, ws + OFF_WKVB, ws + OFF_K, ws + OFF_VT);
  k_q      <<<dim3(64, 8), dim3(256), 0, stream>>>(ws + OFF_LATN, ws + OFF_WQB, ws + OFF_Q);
  k_attn   <<<dim3(64, 16), dim3(256), 0, stream>>>(ws + OFF_Q, ws + OFF_K, ws + OFF_VT, ws + OFF_Y);
  k_proj   <<<dim3(64, 8), dim3(256), 0, stream>>>(ws + OFF_Y, ws + OFF_WPROJ, out);
}